// Round 3
// baseline (8856.032 us; speedup 1.0000x reference)
//
#include <hip/hip_runtime.h>
#include <math.h>

#define NN 100000
#define NE 1600000
#define HD 64
#define NL 3
#define NG 256

__device__ __forceinline__ float rl(float v, int l) {
    return __int_as_float(__builtin_amdgcn_readlane(__float_as_int(v), l));
}

// ---------- CSR build ----------
__global__ __launch_bounds__(256) void k_deg(const int* __restrict__ ei, int* __restrict__ deg) {
    int tid = blockIdx.x * 256 + threadIdx.x;
    int stride = gridDim.x * 256;
    for (int e = tid; e < NE; e += stride)
        atomicAdd(&deg[ei[NE + e]], 1);
}

// single-block exclusive scan of deg[NN] -> rowptr[NN+1], cursor[NN]
__global__ __launch_bounds__(1024) void k_scan(const int* __restrict__ deg,
                                               int* __restrict__ rowptr,
                                               int* __restrict__ cursor) {
    __shared__ int buf[1024];
    __shared__ int s_carry;
    if (threadIdx.x == 0) s_carry = 0;
    __syncthreads();
    for (int base = 0; base < NN; base += 4096) {
        int idx = base + threadIdx.x * 4;
        int d0 = 0, d1 = 0, d2 = 0, d3 = 0;
        if (idx + 3 < NN) {
            const int4 v = *(const int4*)(deg + idx);
            d0 = v.x; d1 = v.y; d2 = v.z; d3 = v.w;
        } else {
            if (idx < NN) d0 = deg[idx];
            if (idx + 1 < NN) d1 = deg[idx + 1];
            if (idx + 2 < NN) d2 = deg[idx + 2];
        }
        int tsum = d0 + d1 + d2 + d3;
        buf[threadIdx.x] = tsum;
        __syncthreads();
        for (int off = 1; off < 1024; off <<= 1) {
            int t = (threadIdx.x >= off) ? buf[threadIdx.x - off] : 0;
            __syncthreads();
            buf[threadIdx.x] += t;
            __syncthreads();
        }
        int incl = buf[threadIdx.x];
        int carry = s_carry;
        int e0 = incl - tsum + carry;
        int e1 = e0 + d0, e2 = e1 + d1, e3 = e2 + d2;
        if (idx < NN)     { rowptr[idx] = e0;     cursor[idx] = e0; }
        if (idx + 1 < NN) { rowptr[idx + 1] = e1; cursor[idx + 1] = e1; }
        if (idx + 2 < NN) { rowptr[idx + 2] = e2; cursor[idx + 2] = e2; }
        if (idx + 3 < NN) { rowptr[idx + 3] = e3; cursor[idx + 3] = e3; }
        __syncthreads();
        if (threadIdx.x == 0) s_carry += buf[1023];
        __syncthreads();
    }
    if (threadIdx.x == 0) rowptr[NN] = s_carry;  // == NE
}

__global__ __launch_bounds__(256) void k_fill(const int* __restrict__ ei,
                                              int* __restrict__ cursor,
                                              int* __restrict__ csr) {
    int tid = blockIdx.x * 256 + threadIdx.x;
    int stride = gridDim.x * 256;
    for (int e = tid; e < NE; e += stride) {
        int s = ei[e];
        int d = ei[NE + e];
        int pos = atomicAdd(&cursor[d], 1);
        csr[pos] = s;
    }
}

// ---------- layer-0 linear: m = x @ W0 ----------
__global__ __launch_bounds__(256) void k_lin0(const float* __restrict__ x,
                                              const float* __restrict__ W,
                                              float* __restrict__ m) {
    __shared__ float Wl[HD * HD];
    for (int i = threadIdx.x; i < HD * HD; i += 256) Wl[i] = W[i];
    __syncthreads();
    int lane = threadIdx.x & 63, wid = threadIdx.x >> 6;
    int step = gridDim.x * 4;
    for (int n = blockIdx.x * 4 + wid; n < NN; n += step) {
        float hv = x[n * HD + lane];
        float acc = 0.f;
        #pragma unroll
        for (int k = 0; k < HD; ++k)
            acc = fmaf(rl(hv, k), Wl[k * HD + lane], acc);
        m[n * HD + lane] = acc;
    }
}

// ---------- fused per-layer: gather + gi + gh + GRU + next-layer linear ----------
// WT[k][0..191]  = Wih^T   (gi weights)
// WT[k][192..383]= Whh^T   (gh weights)
// WL[k][c]       = Wnext   (next layer linear)
__global__ __launch_bounds__(1024) void k_layer(const float* __restrict__ m,
                                                const int* __restrict__ rowptr,
                                                const int* __restrict__ csr,
                                                const float* __restrict__ Wih,
                                                const float* __restrict__ Whh,
                                                const float* __restrict__ bih,
                                                const float* __restrict__ bhh,
                                                const float* __restrict__ h_in,
                                                float* __restrict__ h_out,
                                                const float* __restrict__ Wnext,
                                                float* __restrict__ m_next,
                                                int has_next) {
    __shared__ float WT[HD * 384];
    __shared__ float WL[HD * HD];
    for (int i = threadIdx.x; i < HD * 384; i += 1024) {
        int k = i / 384, j = i % 384;
        WT[i] = (j < 192) ? Wih[j * HD + k] : Whh[(j - 192) * HD + k];
    }
    if (has_next)
        for (int i = threadIdx.x; i < HD * HD; i += 1024) WL[i] = Wnext[i];
    __syncthreads();

    int lane = threadIdx.x & 63;
    int gw = blockIdx.x * 16 + (threadIdx.x >> 6);
    const int nwaves = 256 * 16;

    float bi0 = bih[lane], bi1 = bih[64 + lane], bi2 = bih[128 + lane];
    float bh0 = bhh[lane], bh1 = bhh[64 + lane], bh2 = bhh[128 + lane];

    for (int n = gw; n < NN; n += nwaves) {
        // ---- gather agg = sum of m[src] over in-edges ----
        int beg = rowptr[n], end = rowptr[n + 1];
        float av = 0.f;
        int i = beg;
        for (; i + 4 <= end; i += 4) {
            int s0 = csr[i], s1 = csr[i + 1], s2 = csr[i + 2], s3 = csr[i + 3];
            float v0 = m[(size_t)s0 * HD + lane];
            float v1 = m[(size_t)s1 * HD + lane];
            float v2 = m[(size_t)s2 * HD + lane];
            float v3 = m[(size_t)s3 * HD + lane];
            av += (v0 + v1) + (v2 + v3);
        }
        for (; i < end; ++i)
            av += m[(size_t)csr[i] * HD + lane];

        float hv = h_in[(size_t)n * HD + lane];

        // ---- gi = agg @ Wih^T + bih ; gh = h @ Whh^T + bhh ----
        float a0 = bi0, a1 = bi1, a2 = bi2;
        float g0 = bh0, g1 = bh1, g2 = bh2;
        #pragma unroll
        for (int k = 0; k < HD; ++k) {
            float ak = rl(av, k);
            float hk = rl(hv, k);
            const float* w = &WT[k * 384];
            a0 = fmaf(ak, w[lane], a0);
            a1 = fmaf(ak, w[64 + lane], a1);
            a2 = fmaf(ak, w[128 + lane], a2);
            g0 = fmaf(hk, w[192 + lane], g0);
            g1 = fmaf(hk, w[256 + lane], g1);
            g2 = fmaf(hk, w[320 + lane], g2);
        }

        // ---- GRU pointwise ----
        float r = 1.f / (1.f + expf(-(a0 + g0)));
        float z = 1.f / (1.f + expf(-(a1 + g1)));
        float nq = tanhf(a2 + r * g2);
        float hnew = (1.f - z) * nq + z * hv;
        h_out[(size_t)n * HD + lane] = hnew;

        // ---- next-layer linear: m_next = hnew @ Wnext ----
        if (has_next) {
            float acc = 0.f;
            #pragma unroll
            for (int k = 0; k < HD; ++k)
                acc = fmaf(rl(hnew, k), WL[k * HD + lane], acc);
            m_next[(size_t)n * HD + lane] = acc;
        }
    }
}

// ---------- pool: batch sorted, per-wave contiguous range ----------
__global__ __launch_bounds__(256) void k_pool(const float* __restrict__ h,
                                              const int* __restrict__ batch,
                                              float* __restrict__ out) {
    int gw = (int)((blockIdx.x * 256 + threadIdx.x) >> 6);
    int lane = threadIdx.x & 63;
    int nw = (gridDim.x * 256) >> 6;
    int per = (NN + nw - 1) / nw;
    int s = gw * per;
    int e = s + per; if (e > NN) e = NN;
    if (s >= NN) return;
    float acc = 0.f;
    int cur = batch[s];
    for (int n = s; n < e; ++n) {
        int b = batch[n];
        if (b != cur) {
            atomicAdd(&out[cur * HD + lane], acc);
            acc = 0.f; cur = b;
        }
        acc += h[n * HD + lane];
    }
    atomicAdd(&out[cur * HD + lane], acc);
}

extern "C" void kernel_launch(void* const* d_in, const int* in_sizes, int n_in,
                              void* d_out, int out_size, void* d_ws, size_t ws_size,
                              hipStream_t stream) {
    const float* x      = (const float*)d_in[0];
    const int*   ei     = (const int*)d_in[1];
    const int*   batch  = (const int*)d_in[2];
    const float* weight = (const float*)d_in[3];
    const float* Wih    = (const float*)d_in[4];
    const float* Whh    = (const float*)d_in[5];
    const float* bih    = (const float*)d_in[6];
    const float* bhh    = (const float*)d_in[7];
    float* out = (float*)d_out;

    char* ws = (char*)d_ws;
    const size_t szH = (size_t)NN * HD * sizeof(float);     // 25.6 MB
    float* H    = (float*)(ws);
    float* MA   = (float*)(ws + szH);
    float* MB   = (float*)(ws + 2 * szH);
    int*   deg    = (int*)(ws + 3 * szH);
    int*   rowptr = deg + NN;           // NN+1
    int*   cursor = rowptr + NN + 1;    // NN
    int*   csr    = cursor + NN;        // NE

    // CSR build (edge_index fixed across layers)
    hipMemsetAsync(deg, 0, NN * sizeof(int), stream);
    k_deg<<<2048, 256, 0, stream>>>(ei, deg);
    k_scan<<<1, 1024, 0, stream>>>(deg, rowptr, cursor);
    k_fill<<<2048, 256, 0, stream>>>(ei, cursor, csr);

    // layer 0 messages
    k_lin0<<<1024, 256, 0, stream>>>(x, weight, MA);

    // fused layers
    k_layer<<<256, 1024, 0, stream>>>(MA, rowptr, csr, Wih, Whh, bih, bhh,
                                      x, H, weight + 1 * HD * HD, MB, 1);
    k_layer<<<256, 1024, 0, stream>>>(MB, rowptr, csr, Wih, Whh, bih, bhh,
                                      H, H, weight + 2 * HD * HD, MA, 1);
    k_layer<<<256, 1024, 0, stream>>>(MA, rowptr, csr, Wih, Whh, bih, bhh,
                                      H, H, nullptr, nullptr, 0);

    hipMemsetAsync(out, 0, (size_t)NG * HD * sizeof(float), stream);
    k_pool<<<512, 256, 0, stream>>>(H, batch, out);
}

// Round 4
// 8771.135 us; speedup vs baseline: 1.0097x; 1.0097x over previous
//
#include <hip/hip_runtime.h>
#include <math.h>

#define NN 100000
#define NE 1600000
#define HD 64
#define NL 3
#define NG 256

__device__ __forceinline__ float rl(float v, int l) {
    return __int_as_float(__builtin_amdgcn_readlane(__float_as_int(v), l));
}

// ---------- CSR build ----------
__global__ __launch_bounds__(256) void k_deg(const int* __restrict__ ei, int* __restrict__ deg) {
    int tid = blockIdx.x * 256 + threadIdx.x;
    int stride = gridDim.x * 256;
    for (int e = tid; e < NE; e += stride)
        atomicAdd(&deg[ei[NE + e]], 1);
}

// single-block exclusive scan of deg[NN] -> rowptr-like cursor[NN]
__global__ __launch_bounds__(1024) void k_scan(const int* __restrict__ deg,
                                               int* __restrict__ cursor) {
    __shared__ int buf[1024];
    __shared__ int s_carry;
    if (threadIdx.x == 0) s_carry = 0;
    __syncthreads();
    for (int base = 0; base < NN; base += 4096) {
        int idx = base + threadIdx.x * 4;
        int d0 = 0, d1 = 0, d2 = 0, d3 = 0;
        if (idx + 3 < NN) {
            const int4 v = *(const int4*)(deg + idx);
            d0 = v.x; d1 = v.y; d2 = v.z; d3 = v.w;
        } else {
            if (idx < NN) d0 = deg[idx];
            if (idx + 1 < NN) d1 = deg[idx + 1];
            if (idx + 2 < NN) d2 = deg[idx + 2];
        }
        int tsum = d0 + d1 + d2 + d3;
        buf[threadIdx.x] = tsum;
        __syncthreads();
        for (int off = 1; off < 1024; off <<= 1) {
            int t = (threadIdx.x >= off) ? buf[threadIdx.x - off] : 0;
            __syncthreads();
            buf[threadIdx.x] += t;
            __syncthreads();
        }
        int incl = buf[threadIdx.x];
        int carry = s_carry;
        int e0 = incl - tsum + carry;
        int e1 = e0 + d0, e2 = e1 + d1, e3 = e2 + d2;
        if (idx < NN)     cursor[idx] = e0;
        if (idx + 1 < NN) cursor[idx + 1] = e1;
        if (idx + 2 < NN) cursor[idx + 2] = e2;
        if (idx + 3 < NN) cursor[idx + 3] = e3;
        __syncthreads();
        if (threadIdx.x == 0) s_carry += buf[1023];
        __syncthreads();
    }
}

// fill dst-sorted (src,dst) pairs
__global__ __launch_bounds__(256) void k_fill(const int* __restrict__ ei,
                                              int* __restrict__ cursor,
                                              int2* __restrict__ epack) {
    int tid = blockIdx.x * 256 + threadIdx.x;
    int stride = gridDim.x * 256;
    for (int e = tid; e < NE; e += stride) {
        int s = ei[e];
        int d = ei[NE + e];
        int pos = atomicAdd(&cursor[d], 1);
        epack[pos] = make_int2(s, d);
    }
}

// ---------- layer-0 linear: m = x @ W0 ----------
__global__ __launch_bounds__(256) void k_lin0(const float* __restrict__ x,
                                              const float* __restrict__ W,
                                              float* __restrict__ m) {
    __shared__ float Wl[HD * HD];
    for (int i = threadIdx.x; i < HD * HD; i += 256) Wl[i] = W[i];
    __syncthreads();
    int lane = threadIdx.x & 63, wid = threadIdx.x >> 6;
    int step = gridDim.x * 4;
    for (int n = blockIdx.x * 4 + wid; n < NN; n += step) {
        float hv = x[n * HD + lane];
        float acc = 0.f;
        #pragma unroll
        for (int k = 0; k < HD; ++k)
            acc = fmaf(rl(hv, k), Wl[k * HD + lane], acc);
        m[n * HD + lane] = acc;
    }
}

// ---------- edge-parallel segmented-reduction gather ----------
// epack sorted by dst; wave owns a contiguous edge chunk, lane = channel.
__global__ __launch_bounds__(256) void k_gather(const float* __restrict__ m,
                                                const int2* __restrict__ epack,
                                                float* __restrict__ agg) {
    int gw = (int)((blockIdx.x * 256 + threadIdx.x) >> 6);
    int lane = threadIdx.x & 63;
    int nw = (gridDim.x * 256) >> 6;
    int per = (NE + nw - 1) / nw;
    int s = gw * per;
    int e = s + per; if (e > NE) e = NE;
    if (s >= NE) return;

    float acc = 0.f;
    int cur = epack[s].y;
    int i = s;
    for (; i + 4 <= e; i += 4) {
        int2 p0 = epack[i], p1 = epack[i + 1], p2 = epack[i + 2], p3 = epack[i + 3];
        float v0 = m[(size_t)p0.x * HD + lane];
        float v1 = m[(size_t)p1.x * HD + lane];
        float v2 = m[(size_t)p2.x * HD + lane];
        float v3 = m[(size_t)p3.x * HD + lane];
        if (p0.y != cur) { atomicAdd(&agg[(size_t)cur * HD + lane], acc); acc = 0.f; cur = p0.y; }
        acc += v0;
        if (p1.y != cur) { atomicAdd(&agg[(size_t)cur * HD + lane], acc); acc = 0.f; cur = p1.y; }
        acc += v1;
        if (p2.y != cur) { atomicAdd(&agg[(size_t)cur * HD + lane], acc); acc = 0.f; cur = p2.y; }
        acc += v2;
        if (p3.y != cur) { atomicAdd(&agg[(size_t)cur * HD + lane], acc); acc = 0.f; cur = p3.y; }
        acc += v3;
    }
    for (; i < e; ++i) {
        int2 p = epack[i];
        float v = m[(size_t)p.x * HD + lane];
        if (p.y != cur) { atomicAdd(&agg[(size_t)cur * HD + lane], acc); acc = 0.f; cur = p.y; }
        acc += v;
    }
    atomicAdd(&agg[(size_t)cur * HD + lane], acc);
}

// ---------- fused cell: gi + gh + GRU + next-layer linear ----------
__global__ __launch_bounds__(1024) void k_cell(const float* __restrict__ agg,
                                               const float* __restrict__ Wih,
                                               const float* __restrict__ Whh,
                                               const float* __restrict__ bih,
                                               const float* __restrict__ bhh,
                                               const float* __restrict__ h_in,
                                               float* __restrict__ h_out,
                                               const float* __restrict__ Wnext,
                                               float* __restrict__ m_next,
                                               int has_next) {
    __shared__ float WT[HD * 384];
    __shared__ float WL[HD * HD];
    for (int i = threadIdx.x; i < HD * 384; i += 1024) {
        int k = i / 384, j = i % 384;
        WT[i] = (j < 192) ? Wih[j * HD + k] : Whh[(j - 192) * HD + k];
    }
    if (has_next)
        for (int i = threadIdx.x; i < HD * HD; i += 1024) WL[i] = Wnext[i];
    __syncthreads();

    int lane = threadIdx.x & 63;
    int gw = blockIdx.x * 16 + (threadIdx.x >> 6);
    const int nwaves = 256 * 16;

    float bi0 = bih[lane], bi1 = bih[64 + lane], bi2 = bih[128 + lane];
    float bh0 = bhh[lane], bh1 = bhh[64 + lane], bh2 = bhh[128 + lane];

    for (int n = gw; n < NN; n += nwaves) {
        float av = agg[(size_t)n * HD + lane];
        float hv = h_in[(size_t)n * HD + lane];

        float a0 = bi0, a1 = bi1, a2 = bi2;
        float g0 = bh0, g1 = bh1, g2 = bh2;
        #pragma unroll
        for (int k = 0; k < HD; ++k) {
            float ak = rl(av, k);
            float hk = rl(hv, k);
            const float* w = &WT[k * 384];
            a0 = fmaf(ak, w[lane], a0);
            a1 = fmaf(ak, w[64 + lane], a1);
            a2 = fmaf(ak, w[128 + lane], a2);
            g0 = fmaf(hk, w[192 + lane], g0);
            g1 = fmaf(hk, w[256 + lane], g1);
            g2 = fmaf(hk, w[320 + lane], g2);
        }

        float r = 1.f / (1.f + expf(-(a0 + g0)));
        float z = 1.f / (1.f + expf(-(a1 + g1)));
        float nq = tanhf(a2 + r * g2);
        float hnew = (1.f - z) * nq + z * hv;
        h_out[(size_t)n * HD + lane] = hnew;

        if (has_next) {
            float acc = 0.f;
            #pragma unroll
            for (int k = 0; k < HD; ++k)
                acc = fmaf(rl(hnew, k), WL[k * HD + lane], acc);
            m_next[(size_t)n * HD + lane] = acc;
        }
    }
}

// ---------- pool: batch sorted, per-wave contiguous range ----------
__global__ __launch_bounds__(256) void k_pool(const float* __restrict__ h,
                                              const int* __restrict__ batch,
                                              float* __restrict__ out) {
    int gw = (int)((blockIdx.x * 256 + threadIdx.x) >> 6);
    int lane = threadIdx.x & 63;
    int nw = (gridDim.x * 256) >> 6;
    int per = (NN + nw - 1) / nw;
    int s = gw * per;
    int e = s + per; if (e > NN) e = NN;
    if (s >= NN) return;
    float acc = 0.f;
    int cur = batch[s];
    for (int n = s; n < e; ++n) {
        int b = batch[n];
        if (b != cur) {
            atomicAdd(&out[cur * HD + lane], acc);
            acc = 0.f; cur = b;
        }
        acc += h[n * HD + lane];
    }
    atomicAdd(&out[cur * HD + lane], acc);
}

extern "C" void kernel_launch(void* const* d_in, const int* in_sizes, int n_in,
                              void* d_out, int out_size, void* d_ws, size_t ws_size,
                              hipStream_t stream) {
    const float* x      = (const float*)d_in[0];
    const int*   ei     = (const int*)d_in[1];
    const int*   batch  = (const int*)d_in[2];
    const float* weight = (const float*)d_in[3];
    const float* Wih    = (const float*)d_in[4];
    const float* Whh    = (const float*)d_in[5];
    const float* bih    = (const float*)d_in[6];
    const float* bhh    = (const float*)d_in[7];
    float* out = (float*)d_out;

    char* ws = (char*)d_ws;
    const size_t szH = (size_t)NN * HD * sizeof(float);     // 25.6 MB
    float* H    = (float*)(ws);
    float* MA   = (float*)(ws + szH);
    float* MB   = (float*)(ws + 2 * szH);
    float* AG   = (float*)(ws + 3 * szH);
    int*   deg    = (int*)(ws + 4 * szH);
    int*   cursor = deg + NN;
    int2*  epack  = (int2*)(cursor + NN);   // NE int2 = 12.8 MB

    // CSR-ish build: dst-sorted (src,dst) edge list
    hipMemsetAsync(deg, 0, NN * sizeof(int), stream);
    k_deg<<<2048, 256, 0, stream>>>(ei, deg);
    k_scan<<<1, 1024, 0, stream>>>(deg, cursor);
    k_fill<<<2048, 256, 0, stream>>>(ei, cursor, epack);

    // layer 0 messages
    k_lin0<<<1024, 256, 0, stream>>>(x, weight, MA);

    // layer 1
    hipMemsetAsync(AG, 0, szH, stream);
    k_gather<<<2048, 256, 0, stream>>>(MA, epack, AG);
    k_cell<<<256, 1024, 0, stream>>>(AG, Wih, Whh, bih, bhh, x, H,
                                     weight + 1 * HD * HD, MB, 1);
    // layer 2
    hipMemsetAsync(AG, 0, szH, stream);
    k_gather<<<2048, 256, 0, stream>>>(MB, epack, AG);
    k_cell<<<256, 1024, 0, stream>>>(AG, Wih, Whh, bih, bhh, H, H,
                                     weight + 2 * HD * HD, MA, 1);
    // layer 3
    hipMemsetAsync(AG, 0, szH, stream);
    k_gather<<<2048, 256, 0, stream>>>(MA, epack, AG);
    k_cell<<<256, 1024, 0, stream>>>(AG, Wih, Whh, bih, bhh, H, H,
                                     nullptr, nullptr, 0);

    hipMemsetAsync(out, 0, (size_t)NG * HD * sizeof(float), stream);
    k_pool<<<512, 256, 0, stream>>>(H, batch, out);
}

// Round 5
// 5856.707 us; speedup vs baseline: 1.5121x; 1.4976x over previous
//
#include <hip/hip_runtime.h>
#include <math.h>

#define NN 100000
#define NE 1600000
#define HD 64
#define NG 256

__device__ __forceinline__ float rl(float v, int l) {
    return __int_as_float(__builtin_amdgcn_readlane(__float_as_int(v), l));
}

// pack two f32 into a u32 of two f16 (RNE via _Float16 casts)
__device__ __forceinline__ unsigned pack2(float a, float b) {
    union { _Float16 f[2]; unsigned u; } c;
    c.f[0] = (_Float16)a; c.f[1] = (_Float16)b;
    return c.u;
}
// extract half (hi=0 low, hi=1 high) of u32 as f32
__device__ __forceinline__ float unpack1(unsigned u, int hi) {
    union { unsigned short s; _Float16 f; } c;
    c.s = (unsigned short)(hi ? (u >> 16) : (u & 0xffffu));
    return (float)c.f;
}

// ---------- layer-0 linear: m = x @ W0, output packed f16 ----------
__global__ __launch_bounds__(256) void k_lin0(const float* __restrict__ x,
                                              const float* __restrict__ W,
                                              unsigned* __restrict__ mh) {
    __shared__ float Wl[HD * HD];
    for (int i = threadIdx.x; i < HD * HD; i += 256) Wl[i] = W[i];
    __syncthreads();
    int lane = threadIdx.x & 63, wid = threadIdx.x >> 6;
    int step = gridDim.x * 4;
    for (int n = blockIdx.x * 4 + wid; n < NN; n += step) {
        float hv = x[(size_t)n * HD + lane];
        float acc = 0.f;
        #pragma unroll
        for (int k = 0; k < HD; ++k)
            acc = fmaf(rl(hv, k), Wl[k * HD + lane], acc);
        float nb = __shfl_xor(acc, 1, 64);
        if (!(lane & 1)) mh[(size_t)n * 32 + (lane >> 1)] = pack2(acc, nb);
    }
}

// ---------- edge-parallel scatter with packed-f16 atomics ----------
// thread i -> edge e = i>>5, half2-channel c = i&31.  128B read + 128B atomic per edge.
__global__ __launch_bounds__(256) void k_scat(const unsigned* __restrict__ mh,
                                              const int* __restrict__ ei,
                                              unsigned* __restrict__ aggu) {
    long long tid = (long long)blockIdx.x * 256 + threadIdx.x;
    long long stride = (long long)gridDim.x * 256;
    const long long total = (long long)NE * 32;
    for (long long i = tid; i < total; i += stride) {
        int e = (int)(i >> 5);
        int c = (int)(i & 31);
        int s = ei[e];
        int d = ei[NE + e];
        unsigned v = mh[(size_t)s * 32 + c];
        unsigned* p = &aggu[(size_t)d * 32 + c];
        asm volatile("global_atomic_pk_add_f16 %0, %1, off" :: "v"(p), "v"(v) : "memory");
    }
}

// ---------- fused cell: gi + gh + GRU + next-layer linear ----------
// WT[k][j] (row stride R=385, R%32==1 -> conflict-free transpose staging):
//   j in [0,192)  = Wih^T,  j in [192,384) = Whh^T
__global__ __launch_bounds__(512) void k_cell(const unsigned* __restrict__ aggu,
                                              const float* __restrict__ Wih,
                                              const float* __restrict__ Whh,
                                              const float* __restrict__ bih,
                                              const float* __restrict__ bhh,
                                              const float* __restrict__ h_in,
                                              float* __restrict__ h_out,
                                              const float* __restrict__ Wnext,
                                              unsigned* __restrict__ mh_next,
                                              int has_next) {
    const int R = 385;
    __shared__ float WT[HD * R];
    __shared__ float WL[HD * HD];
    for (int i = threadIdx.x; i < 192 * HD; i += 512) {
        int j = i >> 6, k = i & 63;           // Wih[j][k], coalesced read
        WT[k * R + j] = Wih[i];
    }
    for (int i = threadIdx.x; i < 192 * HD; i += 512) {
        int j = i >> 6, k = i & 63;
        WT[k * R + 192 + j] = Whh[i];
    }
    if (has_next)
        for (int i = threadIdx.x; i < HD * HD; i += 512) WL[i] = Wnext[i];
    __syncthreads();

    int lane = threadIdx.x & 63;
    int gw = blockIdx.x * 8 + (threadIdx.x >> 6);
    const int nwaves = gridDim.x * 8;

    float bi0 = bih[lane], bi1 = bih[64 + lane], bi2 = bih[128 + lane];
    float bh0 = bhh[lane], bh1 = bhh[64 + lane], bh2 = bhh[128 + lane];

    for (int n = gw; n < NN; n += nwaves) {
        unsigned u = aggu[(size_t)n * 32 + (lane >> 1)];
        float av = unpack1(u, lane & 1);
        float hv = h_in[(size_t)n * HD + lane];

        float a0 = bi0, a1 = bi1, a2 = bi2;
        float g0 = bh0, g1 = bh1, g2 = bh2;
        #pragma unroll
        for (int k = 0; k < HD; ++k) {
            float ak = rl(av, k);
            float hk = rl(hv, k);
            const float* w = &WT[k * R];
            a0 = fmaf(ak, w[lane], a0);
            a1 = fmaf(ak, w[64 + lane], a1);
            a2 = fmaf(ak, w[128 + lane], a2);
            g0 = fmaf(hk, w[192 + lane], g0);
            g1 = fmaf(hk, w[256 + lane], g1);
            g2 = fmaf(hk, w[320 + lane], g2);
        }

        float r = 1.f / (1.f + expf(-(a0 + g0)));
        float z = 1.f / (1.f + expf(-(a1 + g1)));
        float nq = tanhf(a2 + r * g2);
        float hnew = (1.f - z) * nq + z * hv;
        h_out[(size_t)n * HD + lane] = hnew;

        if (has_next) {
            float acc = 0.f;
            #pragma unroll
            for (int k = 0; k < HD; ++k)
                acc = fmaf(rl(hnew, k), WL[k * HD + lane], acc);
            float nb = __shfl_xor(acc, 1, 64);
            if (!(lane & 1)) mh_next[(size_t)n * 32 + (lane >> 1)] = pack2(acc, nb);
        }
    }
}

// ---------- pool: batch sorted, per-wave contiguous range ----------
__global__ __launch_bounds__(256) void k_pool(const float* __restrict__ h,
                                              const int* __restrict__ batch,
                                              float* __restrict__ out) {
    int gw = (int)((blockIdx.x * 256 + threadIdx.x) >> 6);
    int lane = threadIdx.x & 63;
    int nw = (gridDim.x * 256) >> 6;
    int per = (NN + nw - 1) / nw;
    int s = gw * per;
    int e = s + per; if (e > NN) e = NN;
    if (s >= NN) return;
    float acc = 0.f;
    int cur = batch[s];
    for (int n = s; n < e; ++n) {
        int b = batch[n];
        if (b != cur) {
            atomicAdd(&out[cur * HD + lane], acc);
            acc = 0.f; cur = b;
        }
        acc += h[n * HD + lane];
    }
    atomicAdd(&out[cur * HD + lane], acc);
}

extern "C" void kernel_launch(void* const* d_in, const int* in_sizes, int n_in,
                              void* d_out, int out_size, void* d_ws, size_t ws_size,
                              hipStream_t stream) {
    const float* x      = (const float*)d_in[0];
    const int*   ei     = (const int*)d_in[1];
    const int*   batch  = (const int*)d_in[2];
    const float* weight = (const float*)d_in[3];
    const float* Wih    = (const float*)d_in[4];
    const float* Whh    = (const float*)d_in[5];
    const float* bih    = (const float*)d_in[6];
    const float* bhh    = (const float*)d_in[7];
    float* out = (float*)d_out;

    char* ws = (char*)d_ws;
    const size_t szH  = (size_t)NN * HD * sizeof(float);   // 25.6 MB
    const size_t szM  = (size_t)NN * 32 * sizeof(unsigned); // 12.8 MB packed f16
    float*    H   = (float*)(ws);
    unsigned* MA  = (unsigned*)(ws + szH);
    unsigned* MB  = (unsigned*)(ws + szH + szM);
    unsigned* AG  = (unsigned*)(ws + szH + 2 * szM);

    // layer 0 messages from x
    k_lin0<<<1024, 256, 0, stream>>>(x, weight, MA);

    // layer 1
    hipMemsetAsync(AG, 0, szM, stream);
    k_scat<<<2048, 256, 0, stream>>>(MA, ei, AG);
    k_cell<<<256, 512, 0, stream>>>(AG, Wih, Whh, bih, bhh, x, H,
                                    weight + 1 * HD * HD, MB, 1);
    // layer 2
    hipMemsetAsync(AG, 0, szM, stream);
    k_scat<<<2048, 256, 0, stream>>>(MB, ei, AG);
    k_cell<<<256, 512, 0, stream>>>(AG, Wih, Whh, bih, bhh, H, H,
                                    weight + 2 * HD * HD, MA, 1);
    // layer 3
    hipMemsetAsync(AG, 0, szM, stream);
    k_scat<<<2048, 256, 0, stream>>>(MA, ei, AG);
    k_cell<<<256, 512, 0, stream>>>(AG, Wih, Whh, bih, bhh, H, H,
                                    nullptr, nullptr, 0);

    hipMemsetAsync(out, 0, (size_t)NG * HD * sizeof(float), stream);
    k_pool<<<512, 256, 0, stream>>>(H, batch, out);
}